// Round 3
// baseline (3724.537 us; speedup 1.0000x reference)
//
#include <hip/hip_runtime.h>
#include <math.h>

// Problem constants
#define BB 8
#define NN 16384      // H*W = 128*128
#define CCH 256       // input channels
#define OCH 512       // conv output channels = INNER
#define IMG 128

typedef float4 f4;
typedef _Float16 half8 __attribute__((ext_vector_type(8)));
typedef _Float16 half4v __attribute__((ext_vector_type(4)));
typedef float floatx4 __attribute__((ext_vector_type(4)));

__device__ __forceinline__ f4 ldg4(const float* p) { return *(const f4*)p; }

// ---------------------------------------------------------------------------
// pad_split: x fp32 [8][128][128][256] -> zero-haloed fp16 hi/lo [8][130][130][256]
// ---------------------------------------------------------------------------
__global__ __launch_bounds__(256) void pad_split(const float* __restrict__ x,
                                                 _Float16* __restrict__ xh,
                                                 _Float16* __restrict__ xl) {
  int tid = blockIdx.x * 256 + threadIdx.x;   // 8*130*130*32 = 4,326,400 exact
  int c8 = tid & 31;
  int p = tid >> 5;
  int xcol = p % 130;
  int p2 = p / 130;
  int y = p2 % 130;
  int b = p2 / 130;
  half8 hv, lv;
#pragma unroll
  for (int j = 0; j < 8; ++j) { hv[j] = (_Float16)0.f; lv[j] = (_Float16)0.f; }
  if (y >= 1 && y <= 128 && xcol >= 1 && xcol <= 128) {
    const float* src = x + ((size_t)(b * 128 + y - 1) * 128 + (xcol - 1)) * 256 + c8 * 8;
    f4 v0 = ldg4(src);
    f4 v1 = ldg4(src + 4);
    float vv[8] = {v0.x, v0.y, v0.z, v0.w, v1.x, v1.y, v1.z, v1.w};
#pragma unroll
    for (int j = 0; j < 8; ++j) {
      _Float16 h = (_Float16)vv[j];
      hv[j] = h;
      lv[j] = (_Float16)(vv[j] - (float)h);
    }
  }
  size_t dst = (size_t)p * 256 + c8 * 8;
  *(half8*)(xh + dst) = hv;
  *(half8*)(xl + dst) = lv;
}

// ---------------------------------------------------------------------------
// wsplit: conv_w fp32 [512][256][3][3] -> fp16 hi/lo Wt[tap][o][c]
// ---------------------------------------------------------------------------
__global__ __launch_bounds__(256) void wsplit(const float* __restrict__ cw,
                                              _Float16* __restrict__ wh,
                                              _Float16* __restrict__ wl) {
  int tid = blockIdx.x * 256 + threadIdx.x;   // 9*512*32 = 147,456 exact
  int c8 = tid & 31;
  int o = (tid >> 5) & 511;
  int tap = tid >> 14;
  half8 hv, lv;
#pragma unroll
  for (int j = 0; j < 8; ++j) {
    float v = cw[(size_t)o * 2304 + (c8 * 8 + j) * 9 + tap];
    _Float16 h = (_Float16)v;
    hv[j] = h;
    lv[j] = (_Float16)(v - (float)h);
  }
  size_t dst = ((size_t)tap * 512 + o) * 256 + c8 * 8;
  *(half8*)(wh + dst) = hv;
  *(half8*)(wl + dst) = lv;
}

// ---------------------------------------------------------------------------
// fsplit: generic fp32 -> fp16 hi/lo elementwise (for W1, W2)
// ---------------------------------------------------------------------------
__global__ __launch_bounds__(256) void fsplit(const float* __restrict__ s,
                                              _Float16* __restrict__ h,
                                              _Float16* __restrict__ l, int n) {
  int i = blockIdx.x * 256 + threadIdx.x;
  if (i < n) {
    float v = s[i];
    _Float16 hh = (_Float16)v;
    h[i] = hh;
    l[i] = (_Float16)(v - (float)hh);
  }
}

// ---------------------------------------------------------------------------
// conv_mfma v3: LDS-free, barrier-free implicit GEMM. A and B fragments loaded
// global->VGPR directly (vmcnt-pipelined by the compiler, no __syncthreads).
// Block: 128 px (one row) x 128 och; 4 waves x (64x64 = 4x4 16x16x32 tiles).
// 3-term fp16-split MFMA. XCD-banded grid: lin&7 -> batch, rows ascend,
// obase innermost so tap/A reuse is L2-resident per XCD.
// ---------------------------------------------------------------------------
__global__ __launch_bounds__(256) void conv_mfma(const _Float16* __restrict__ xph,
                                                 const _Float16* __restrict__ xpl,
                                                 const _Float16* __restrict__ wh,
                                                 const _Float16* __restrict__ wl,
                                                 const float* __restrict__ cb,
                                                 float* __restrict__ xc) {
  const int lin = blockIdx.x;                // 4096
  const int bi = lin & 7;                    // XCD band = batch
  const int within = lin >> 3;               // 0..511
  const int obase = (within & 3) * 128;      // innermost: 4 obase share A in L2
  const int yy = within >> 2;                // 0..127 ascending per XCD
  const int t = threadIdx.x;
  const int w = t >> 6, lane = t & 63;
  const int wm = (w & 1) * 64, wn = (w >> 1) * 64;
  const int l15 = lane & 15, k8o = (lane >> 4) * 8;

  floatx4 acc[4][4];
#pragma unroll
  for (int i = 0; i < 4; ++i)
#pragma unroll
    for (int j = 0; j < 4; ++j) acc[i][j] = (floatx4){0.f, 0.f, 0.f, 0.f};

  const size_t arow0 = (size_t)(bi * 130 + yy) * 130 * 256;

  for (int tap = 0; tap < 9; ++tap) {
    const int dy = tap / 3, dx = tap % 3;
    const size_t aoff = arow0 + (size_t)(dy * 130 + dx) * 256 + (size_t)(wm + l15) * 256 + k8o;
    const _Float16* ap = xph + aoff;
    const _Float16* alp = xpl + aoff;
    const size_t boff = ((size_t)tap * 512 + obase + wn + l15) * 256 + k8o;
    const _Float16* bp = wh + boff;
    const _Float16* blp = wl + boff;
#pragma unroll 2
    for (int cc = 0; cc < 8; ++cc) {
      const int c0 = cc * 32;
      half8 ah[4], al[4], bh[4], bl[4];
#pragma unroll
      for (int mt = 0; mt < 4; ++mt) {
        ah[mt] = *(const half8*)(ap + mt * 16 * 256 + c0);
        al[mt] = *(const half8*)(alp + mt * 16 * 256 + c0);
      }
#pragma unroll
      for (int nt = 0; nt < 4; ++nt) {
        bh[nt] = *(const half8*)(bp + nt * 16 * 256 + c0);
        bl[nt] = *(const half8*)(blp + nt * 16 * 256 + c0);
      }
#pragma unroll
      for (int mt = 0; mt < 4; ++mt)
#pragma unroll
        for (int nt = 0; nt < 4; ++nt) {
          acc[mt][nt] = __builtin_amdgcn_mfma_f32_16x16x32_f16(ah[mt], bh[nt], acc[mt][nt], 0, 0, 0);
          acc[mt][nt] = __builtin_amdgcn_mfma_f32_16x16x32_f16(al[mt], bh[nt], acc[mt][nt], 0, 0, 0);
          acc[mt][nt] = __builtin_amdgcn_mfma_f32_16x16x32_f16(ah[mt], bl[nt], acc[mt][nt], 0, 0, 0);
        }
    }
  }

  // epilogue: C/D layout col=lane&15, row=(lane>>4)*4+reg
  const int col = lane & 15;
  const int qr = (lane >> 4) * 4;
#pragma unroll
  for (int nt = 0; nt < 4; ++nt) {
    const int och = obase + wn + nt * 16 + col;
    const float bias = cb[och];
#pragma unroll
    for (int mt = 0; mt < 4; ++mt)
#pragma unroll
      for (int r = 0; r < 4; ++r) {
        int m = wm + mt * 16 + qr + r;
        xc[((size_t)bi * NN + (size_t)yy * IMG + m) * OCH + och] = acc[mt][nt][r] + bias;
      }
  }
}

// ---------------------------------------------------------------------------
// Kernel B: fused K/V projection + kv accumulation (never materializes K,V).
// ---------------------------------------------------------------------------
__global__ __launch_bounds__(256) void bkern(const float* __restrict__ xc,
                                             const float* __restrict__ Wk,
                                             const float* __restrict__ Wv,
                                             float* __restrict__ P,
                                             float* __restrict__ PS) {
  __shared__ float wkT[4096];
  __shared__ float wvT[4096];
  __shared__ float red[64 * 65];
  __shared__ float Sred[64];
  const int t = threadIdx.x;
  const int bh = blockIdx.x >> 3;
  const int sp = blockIdx.x & 7;
  const int b = bh >> 3, h = bh & 7;
  {
    int d4 = (t & 15) * 4;
#pragma unroll
    for (int p = 0; p < 4; ++p) {
      int kr = (t >> 4) + p * 16;
      f4 wk = ldg4(Wk + kr * 64 + d4);
      f4 wv = ldg4(Wv + kr * 64 + d4);
      wkT[(d4 + 0) * 64 + kr] = wk.x; wkT[(d4 + 1) * 64 + kr] = wk.y;
      wkT[(d4 + 2) * 64 + kr] = wk.z; wkT[(d4 + 3) * 64 + kr] = wk.w;
      wvT[(d4 + 0) * 64 + kr] = wv.x; wvT[(d4 + 1) * 64 + kr] = wv.y;
      wvT[(d4 + 2) * 64 + kr] = wv.z; wvT[(d4 + 3) * 64 + kr] = wv.w;
    }
  }
  __syncthreads();
  const int lane = t & 63, w = t >> 6;
  float macc[64];
#pragma unroll
  for (int d = 0; d < 64; ++d) macc[d] = 0.f;
  float ssum = 0.f;
  const int nbase = sp * 2048 + w * 512;
  const float* xrow = xc + (size_t)(b * NN + nbase) * OCH + h * 64 + lane;
  for (int r = 0; r < 512; ++r) {
    float xv = *xrow;
    xrow += OCH;
    int xi = __float_as_int(xv);
    float klog = 0.f, vv = 0.f;
#pragma unroll
    for (int d = 0; d < 64; ++d) {
      float xd = __int_as_float(__builtin_amdgcn_readlane(xi, d));
      klog = fmaf(xd, wkT[d * 64 + lane], klog);
      vv = fmaf(xd, wvT[d * 64 + lane], vv);
    }
    float ek = expf(klog);
    ssum += ek;
    int ei = __float_as_int(ek);
#pragma unroll
    for (int d = 0; d < 64; ++d) {
      float ekd = __int_as_float(__builtin_amdgcn_readlane(ei, d));
      macc[d] = fmaf(ekd, vv, macc[d]);
    }
  }
  for (int ww = 0; ww < 4; ++ww) {
    if (w == ww) {
      if (ww == 0) {
#pragma unroll
        for (int d = 0; d < 64; ++d) red[d * 65 + lane] = macc[d];
        Sred[lane] = ssum;
      } else {
#pragma unroll
        for (int d = 0; d < 64; ++d) red[d * 65 + lane] += macc[d];
        Sred[lane] += ssum;
      }
    }
    __syncthreads();
  }
  float* Pp = P + (size_t)blockIdx.x * 4096;
#pragma unroll
  for (int e = 0; e < 16; ++e) {
    int idx = t + e * 256;
    Pp[idx] = red[(idx >> 6) * 65 + (idx & 63)];
  }
  if (t < 64) PS[blockIdx.x * 64 + t] = Sred[t];
}

// ---------------------------------------------------------------------------
// Kernel C: kv[bh][d][c] = sum_sp P / sum_sp S[d]
// ---------------------------------------------------------------------------
__global__ __launch_bounds__(256) void ckern(const float* __restrict__ P,
                                             const float* __restrict__ PS,
                                             float* __restrict__ kvb) {
  int bh = blockIdx.x, t = threadIdx.x;
#pragma unroll
  for (int e = 0; e < 16; ++e) {
    int idx = t + e * 256;
    int d = idx >> 6;
    float m = 0.f, s = 0.f;
    for (int sp = 0; sp < 8; ++sp) {
      m += P[(size_t)(bh * 8 + sp) * 4096 + idx];
      s += PS[(bh * 8 + sp) * 64 + d];
    }
    kvb[(size_t)bh * 4096 + idx] = m / s;
  }
}

// ---------------------------------------------------------------------------
// Kernel D1: per 64-row tile, per head: qlog = X@WqT, softmax over kr,
// qkv = softmax(q) @ kv. Writes result IN-PLACE over xc rows as PACKED fp16
// hi/lo: per row (1024 halfs): head hh -> hi[64] at hh*128, lo[64] at hh*128+64.
// ---------------------------------------------------------------------------
__global__ __launch_bounds__(256) void d1kern(float* __restrict__ xc,
                                              const float* __restrict__ Wq,
                                              const float* __restrict__ kvb) {
  __shared__ float WqT[64 * 68];
  __shared__ float kvs[64 * 68];
  __shared__ float Xs[64 * 68];
  __shared__ float Et[64 * 68];
  __shared__ float rs[64];
  const int t = threadIdx.x;
  const int tx = t & 15, ty = t >> 4;
  const int row0 = blockIdx.x * 64;
  const int b = row0 >> 14;
  _Float16* xch = (_Float16*)xc;
  {
    int d4 = (t & 15) * 4;
#pragma unroll
    for (int p = 0; p < 4; ++p) {
      int kr = (t >> 4) + p * 16;
      f4 wq = ldg4(Wq + kr * 64 + d4);
      WqT[(d4 + 0) * 68 + kr] = wq.x; WqT[(d4 + 1) * 68 + kr] = wq.y;
      WqT[(d4 + 2) * 68 + kr] = wq.z; WqT[(d4 + 3) * 68 + kr] = wq.w;
    }
  }
  for (int h = 0; h < 8; ++h) {
    __syncthreads();
#pragma unroll
    for (int p = 0; p < 4; ++p) {
      int lin4 = t + p * 256;
      int d = lin4 >> 4;
      int c = (lin4 & 15) * 4;
      f4 kv = ldg4(kvb + (size_t)(b * 8 + h) * 4096 + lin4 * 4);
      *(f4*)&kvs[d * 68 + c] = kv;
    }
    {
      int d4 = (t & 15) * 4;
#pragma unroll
      for (int p = 0; p < 4; ++p) {
        int r = (t >> 4) + p * 16;
        f4 xv = ldg4(xc + (size_t)(row0 + r) * OCH + h * 64 + d4);
        Xs[(d4 + 0) * 68 + r] = xv.x; Xs[(d4 + 1) * 68 + r] = xv.y;
        Xs[(d4 + 2) * 68 + r] = xv.z; Xs[(d4 + 3) * 68 + r] = xv.w;
      }
    }
    __syncthreads();
    float a1[4][4];
#pragma unroll
    for (int i = 0; i < 4; ++i)
#pragma unroll
      for (int j = 0; j < 4; ++j) a1[i][j] = 0.f;
    const f4* Xs4 = (const f4*)Xs;
    const f4* Wq4 = (const f4*)WqT;
#pragma unroll 8
    for (int k = 0; k < 64; ++k) {
      f4 a = Xs4[k * 17 + ty];
      f4 bq = Wq4[k * 17 + tx];
      float av[4] = {a.x, a.y, a.z, a.w};
      float bv[4] = {bq.x, bq.y, bq.z, bq.w};
#pragma unroll
      for (int i = 0; i < 4; ++i)
#pragma unroll
        for (int j = 0; j < 4; ++j) a1[i][j] = fmaf(av[i], bv[j], a1[i][j]);
    }
#pragma unroll
    for (int i = 0; i < 4; ++i)
#pragma unroll
      for (int j = 0; j < 4; ++j)
        Et[(tx * 4 + j) * 68 + ty * 4 + i] = expf(a1[i][j]);
    __syncthreads();
    if (t < 64) {
      float s = 0.f;
      for (int kr = 0; kr < 64; ++kr) s += Et[kr * 68 + t];
      rs[t] = s;
    }
    __syncthreads();
    float a2[4][4];
#pragma unroll
    for (int i = 0; i < 4; ++i)
#pragma unroll
      for (int j = 0; j < 4; ++j) a2[i][j] = 0.f;
    const f4* Et4 = (const f4*)Et;
    const f4* kv4 = (const f4*)kvs;
#pragma unroll 8
    for (int k = 0; k < 64; ++k) {
      f4 a = Et4[k * 17 + ty];
      f4 bv = kv4[k * 17 + tx];
      float av[4] = {a.x, a.y, a.z, a.w};
      float bb[4] = {bv.x, bv.y, bv.z, bv.w};
#pragma unroll
      for (int i = 0; i < 4; ++i)
#pragma unroll
        for (int j = 0; j < 4; ++j) a2[i][j] = fmaf(av[i], bb[j], a2[i][j]);
    }
#pragma unroll
    for (int i = 0; i < 4; ++i) {
      float inv = 1.0f / rs[ty * 4 + i];
      half4v hv, lv;
#pragma unroll
      for (int j = 0; j < 4; ++j) {
        float v = a2[i][j] * inv;
        _Float16 hh = (_Float16)v;
        hv[j] = hh;
        lv[j] = (_Float16)(v - (float)hh);
      }
      size_t rb = (size_t)(row0 + ty * 4 + i) * 1024 + h * 128 + tx * 4;
      *(half4v*)(xch + rb) = hv;
      *(half4v*)(xch + rb + 64) = lv;
    }
  }
}

// ---------------------------------------------------------------------------
// gemm16: LDS-free barrier-free fp16x2-split MFMA GEMM, 128 rows x 128 j per
// block, 4 waves x 64x64. A packed fp16 hi/lo; W pre-split [j][k].
// MODE 0: A headpacked (row stride 1024 halfs; hi at (k>>6)*128+(k&63), lo +64)
// MODE 1: A flatpacked (row stride 2*KT halfs; hi at k, lo at KT+k)
// OUTMODE 0: gelu -> flatpacked fp16 hi/lo (row [hi NOUT][lo NOUT])
// OUTMODE 1: fp32 out, row stride NOUT
// ---------------------------------------------------------------------------
template <int KT, int MODE, int OUTMODE, int NOUT>
__global__ __launch_bounds__(256) void gemm16(const _Float16* __restrict__ A,
                                              const _Float16* __restrict__ Wh,
                                              const _Float16* __restrict__ Wl,
                                              const float* __restrict__ bias,
                                              void* __restrict__ out) {
  const int lin = blockIdx.x;
  const int xcd = lin & 7;
  const int within = lin >> 3;
  const int NJB = NOUT / 128;
  const int jb = within & (NJB - 1);
  const int rowblk = xcd * 128 + (within / NJB);
  const int row0 = rowblk * 128;
  const int jbase = jb * 128;
  const int RS = (MODE == 0) ? 1024 : 2 * KT;

  const int t = threadIdx.x;
  const int w = t >> 6, lane = t & 63;
  const int wm = (w & 1) * 64, wn = (w >> 1) * 64;
  const int l15 = lane & 15, k8o = (lane >> 4) * 8;

  floatx4 acc[4][4];
#pragma unroll
  for (int i = 0; i < 4; ++i)
#pragma unroll
    for (int j = 0; j < 4; ++j) acc[i][j] = (floatx4){0.f, 0.f, 0.f, 0.f};

  const _Float16* ab = A + (size_t)(row0 + wm + l15) * RS + k8o;
  const size_t wb_off = (size_t)(jbase + wn + l15) * KT + k8o;
  const _Float16* bp = Wh + wb_off;
  const _Float16* blp = Wl + wb_off;

#pragma unroll 2
  for (int cc = 0; cc < KT / 32; ++cc) {
    const int c0 = cc * 32;
    int hio, loo;
    if (MODE == 0) { hio = (c0 >> 6) * 128 + (c0 & 63); loo = hio + 64; }
    else { hio = c0; loo = KT + c0; }
    half8 ah[4], al[4], bh[4], bl[4];
#pragma unroll
    for (int mt = 0; mt < 4; ++mt) {
      ah[mt] = *(const half8*)(ab + (size_t)mt * 16 * RS + hio);
      al[mt] = *(const half8*)(ab + (size_t)mt * 16 * RS + loo);
    }
#pragma unroll
    for (int nt = 0; nt < 4; ++nt) {
      bh[nt] = *(const half8*)(bp + nt * 16 * KT + c0);
      bl[nt] = *(const half8*)(blp + nt * 16 * KT + c0);
    }
#pragma unroll
    for (int mt = 0; mt < 4; ++mt)
#pragma unroll
      for (int nt = 0; nt < 4; ++nt) {
        acc[mt][nt] = __builtin_amdgcn_mfma_f32_16x16x32_f16(ah[mt], bh[nt], acc[mt][nt], 0, 0, 0);
        acc[mt][nt] = __builtin_amdgcn_mfma_f32_16x16x32_f16(al[mt], bh[nt], acc[mt][nt], 0, 0, 0);
        acc[mt][nt] = __builtin_amdgcn_mfma_f32_16x16x32_f16(ah[mt], bl[nt], acc[mt][nt], 0, 0, 0);
      }
  }

  const int col = lane & 15;
  const int qr = (lane >> 4) * 4;
#pragma unroll
  for (int nt = 0; nt < 4; ++nt) {
    const int j = jbase + wn + nt * 16 + col;
    const float bj = bias[j];
#pragma unroll
    for (int mt = 0; mt < 4; ++mt)
#pragma unroll
      for (int r = 0; r < 4; ++r) {
        const int row = row0 + wm + mt * 16 + qr + r;
        float v = acc[mt][nt][r] + bj;
        if (OUTMODE == 0) {
          v = 0.5f * v * (1.0f + erff(v * 0.70710678118654752440f));
          _Float16 hh = (_Float16)v;
          _Float16 ll = (_Float16)(v - (float)hh);
          _Float16* o = (_Float16*)out + (size_t)row * (2 * NOUT) + j;
          o[0] = hh;
          o[NOUT] = ll;
        } else {
          ((float*)out)[(size_t)row * NOUT + j] = v;
        }
      }
  }
}

// ---------------------------------------------------------------------------
extern "C" void kernel_launch(void* const* d_in, const int* in_sizes, int n_in,
                              void* d_out, int out_size, void* d_ws, size_t ws_size,
                              hipStream_t stream) {
  const float* x  = (const float*)d_in[0];
  const float* cw = (const float*)d_in[1];
  const float* cb = (const float*)d_in[2];
  const float* Wq = (const float*)d_in[3];
  const float* Wk = (const float*)d_in[4];
  const float* Wv = (const float*)d_in[5];
  const float* W1 = (const float*)d_in[6];
  const float* b1 = (const float*)d_in[7];
  const float* W2 = (const float*)d_in[8];
  const float* b2 = (const float*)d_in[9];
  float* out = (float*)d_out;
  float* ws = (float*)d_ws;

  // region0 (34,611,200 f32), time-multiplexed:
  //   conv phase: xph/xpl fp16 (8*130*130*256 halfs each)
  //   attn phase: P + PS + kvb
  //   mlp phase:  y1 packed fp16 (131072 rows x [hi256|lo256] halfs = 134MB)
  _Float16* xph = (_Float16*)ws;
  _Float16* xpl = (_Float16*)(ws + 17305600);
  float* P   = ws;
  float* PS  = ws + 2097152;
  float* kvb = ws + 2129920;
  _Float16* y1 = (_Float16*)ws;
  float* xc  = ws + 34611200;                  // 67,108,864 f32 (B,N,512); after
                                               // d1kern: packed fp16 hi/lo in place
  _Float16* wh  = (_Float16*)(ws + 101720064); // 1,179,648 halfs
  _Float16* wl  = (_Float16*)(ws + 102309888);
  _Float16* w1h = (_Float16*)(ws + 102899712); // 131,072 halfs
  _Float16* w1l = (_Float16*)(ws + 102965248);
  _Float16* w2h = (_Float16*)(ws + 103030784); // 65,536 halfs
  _Float16* w2l = (_Float16*)(ws + 103063552);
  // end: 103,096,320 f32 = 412.4 MB

  pad_split<<<16900, 256, 0, stream>>>(x, xph, xpl);
  wsplit<<<576, 256, 0, stream>>>(cw, wh, wl);
  fsplit<<<512, 256, 0, stream>>>(W1, w1h, w1l, 131072);
  fsplit<<<256, 256, 0, stream>>>(W2, w2h, w2l, 65536);
  conv_mfma<<<4096, 256, 0, stream>>>(xph, xpl, wh, wl, cb, xc);
  bkern<<<512, 256, 0, stream>>>(xc, Wk, Wv, P, PS);
  ckern<<<64, 256, 0, stream>>>(P, PS, kvb);
  d1kern<<<2048, 256, 0, stream>>>(xc, Wq, kvb);
  // mlp1: A = packed xc (headpack), K=512, NOUT=256, gelu -> y1 packed
  gemm16<512, 0, 0, 256><<<2048, 256, 0, stream>>>((const _Float16*)xc, w1h, w1l, b1, y1);
  // mlp2: A = y1 (flatpack), K=256, NOUT=256, fp32 -> out
  gemm16<256, 1, 1, 256><<<2048, 256, 0, stream>>>(y1, w2h, w2l, b2, out);
}